// Round 2
// baseline (928.679 us; speedup 1.0000x reference)
//
#include <hip/hip_runtime.h>
#include <stdint.h>

typedef unsigned int u32;

#define N_NODES  100000
#define N_EDGES  1600000
#define DFEAT    128
#define N_GRAPHS 512

#define NB_N 391      // ceil(N_NODES/256)
#define NB_E 6250     // N_EDGES/256 exactly

// ---------------- int64-vs-int32 detection ----------------
// If edge_index is int64 (values < 2^31, nonneg), the odd 32-bit words of the
// first 64 entries are all zero. For int32 data those words are uniform edge
// values (P(all 64 == 0) ~ 1e-320). Mode flag lives in ws; kernels branch
// uniformly on it (no host sync -> graph-capture safe).
__global__ void detect_k(const int* __restrict__ ei, int* __restrict__ flag) {
  if (threadIdx.x == 0 && blockIdx.x == 0) {
    int any = 0;
    for (int i = 0; i < 64; i++) any |= ei[2 * i + 1];
    *flag = (any == 0) ? 1 : 0;
  }
}

__device__ __forceinline__ int ld_src(const int* ei, int m, int e) {
  return m ? ei[2 * e] : ei[e];
}
__device__ __forceinline__ int ld_dst(const int* ei, int m, int e) {
  return m ? ei[2 * (N_EDGES + e)] : ei[N_EDGES + e];
}

// ---------------- setup kernels ----------------

__global__ void init_deg_k(int* __restrict__ deg) {
  int i = blockIdx.x * 256 + threadIdx.x;
  if (i < N_NODES) deg[i] = 1;                 // self-loop
}

__global__ void count_k(const int* __restrict__ ei, const int* __restrict__ flag,
                        int* __restrict__ deg) {
  int e = blockIdx.x * 256 + threadIdx.x;      // grid covers exactly N_EDGES
  int m = *flag;
  atomicAdd(&deg[ld_dst(ei, m, e)], 1);
}

// exclusive scan of (deg-1): block-local pass
__global__ __launch_bounds__(256) void scan1_k(const int* __restrict__ deg,
                                               int* __restrict__ rowptr,
                                               int* __restrict__ blksum) {
  __shared__ int tmp[256];
  int t = threadIdx.x;
  int gid = blockIdx.x * 256 + t;
  int v = (gid < N_NODES) ? (deg[gid] - 1) : 0;
  tmp[t] = v;
  for (int off = 1; off < 256; off <<= 1) {
    __syncthreads();
    int add = (t >= off) ? tmp[t - off] : 0;
    __syncthreads();
    tmp[t] += add;
  }
  __syncthreads();
  if (gid < N_NODES) rowptr[gid] = tmp[t] - v;   // exclusive within block
  if (t == 255) blksum[blockIdx.x] = tmp[255];
}

__global__ __launch_bounds__(512) void scan2_k(int* __restrict__ blksum) {
  __shared__ int tmp[512];
  int t = threadIdx.x;
  int v = (t < NB_N) ? blksum[t] : 0;
  tmp[t] = v;
  for (int off = 1; off < 512; off <<= 1) {
    __syncthreads();
    int add = (t >= off) ? tmp[t - off] : 0;
    __syncthreads();
    tmp[t] += add;
  }
  __syncthreads();
  if (t < NB_N) blksum[t] = tmp[t] - v;          // exclusive
}

__global__ __launch_bounds__(256) void scan3_k(const int* __restrict__ deg,
                                               int* __restrict__ rowptr,
                                               int* __restrict__ cursor,
                                               float* __restrict__ dinv,
                                               const int* __restrict__ blksum) {
  int gid = blockIdx.x * 256 + threadIdx.x;
  if (gid < N_NODES) {
    int v = rowptr[gid] + blksum[blockIdx.x];
    rowptr[gid] = v;
    cursor[gid] = v;
    dinv[gid] = rsqrtf((float)deg[gid]);
  }
  if (gid == 0) rowptr[N_NODES] = N_EDGES;
}

__global__ void fill_k(const int* __restrict__ ei, const int* __restrict__ flag,
                       int* __restrict__ cursor, int* __restrict__ colarr) {
  int e = blockIdx.x * 256 + threadIdx.x;
  int m = *flag;
  int d = ld_dst(ei, m, e);
  int pos = atomicAdd(&cursor[d], 1);
  colarr[pos] = ld_src(ei, m, e);
}

// ---------------- GEMM: Y[r,:] = (X @ W)[r,:] * dinv[r], all f32 ----------------
// 64 rows x 128 cols per block, K blocked by 32. Thread (rg,cg): rg=tid>>5 owns
// rows rg*8..+7, cg=tid&31 owns cols {cg, cg+32, cg+64, cg+96} (strided ->
// conflict-free b32 sW reads, coalesced stores).
__global__ __launch_bounds__(256, 1) void gemm_scale_k(const float* __restrict__ X,
                                                       const float* __restrict__ W,
                                                       const float* __restrict__ dinv,
                                                       float* __restrict__ Y, int nrows) {
  __shared__ float sW[32][132];   // [k][c], pitch 132 floats (528B, 16B-mult)
  __shared__ float sX[64][36];    // [row][k], pitch 36 floats (144B, 16B-mult)
  int tid = threadIdx.x;
  int r0 = blockIdx.x * 64;
  int rg = tid >> 5;              // 0..7
  int cg = tid & 31;              // 0..31

  float acc[8][4];
#pragma unroll
  for (int j = 0; j < 8; j++)
#pragma unroll
    for (int c = 0; c < 4; c++) acc[j][c] = 0.f;

  for (int kb = 0; kb < DFEAT; kb += 32) {
    __syncthreads();
    // stage X tile: 64 rows x 32 k = 512 float4, 2 per thread
#pragma unroll
    for (int p = 0; p < 2; p++) {
      int q = tid + p * 256;
      int row = q >> 3;
      int ko = (q & 7) * 4;
      float4 v = make_float4(0.f, 0.f, 0.f, 0.f);
      int gr = r0 + row;
      if (gr < nrows) v = *(const float4*)(X + (size_t)gr * DFEAT + kb + ko);
      *(float4*)(&sX[row][ko]) = v;
    }
    // stage W block: 32 k x 128 c = 1024 float4, 4 per thread
#pragma unroll
    for (int p = 0; p < 4; p++) {
      int q = tid + p * 256;
      int k = q >> 5;
      int co = (q & 31) * 4;
      *(float4*)(&sW[k][co]) = *(const float4*)(W + (size_t)(kb + k) * DFEAT + co);
    }
    __syncthreads();

#pragma unroll
    for (int kk0 = 0; kk0 < 32; kk0 += 4) {
      float4 a4[8];
#pragma unroll
      for (int j = 0; j < 8; j++) a4[j] = *(const float4*)(&sX[rg * 8 + j][kk0]);
#pragma unroll
      for (int kk = 0; kk < 4; kk++) {
        float w0 = sW[kk0 + kk][cg];
        float w1 = sW[kk0 + kk][cg + 32];
        float w2 = sW[kk0 + kk][cg + 64];
        float w3 = sW[kk0 + kk][cg + 96];
#pragma unroll
        for (int j = 0; j < 8; j++) {
          float a = ((const float*)&a4[j])[kk];
          acc[j][0] = fmaf(a, w0, acc[j][0]);
          acc[j][1] = fmaf(a, w1, acc[j][1]);
          acc[j][2] = fmaf(a, w2, acc[j][2]);
          acc[j][3] = fmaf(a, w3, acc[j][3]);
        }
      }
    }
  }

#pragma unroll
  for (int j = 0; j < 8; j++) {
    int gr = r0 + rg * 8 + j;
    if (gr < nrows) {
      float dv = dinv[gr];
#pragma unroll
      for (int c = 0; c < 4; c++)
        Y[(size_t)gr * DFEAT + cg + 32 * c] = acc[j][c] * dv;
    }
  }
}

// ---------------- aggregation: out[i] = act(dinv[i]*(hs[i] + sum_in hs[src]) + b) ----------------
__global__ __launch_bounds__(256) void agg_k(const float* __restrict__ HS,
                                             const float* __restrict__ dinv,
                                             const int* __restrict__ rowptr,
                                             const int* __restrict__ colidx,
                                             const float* __restrict__ bias,
                                             float* __restrict__ OUT, int do_relu) {
  int node = blockIdx.x * 4 + (threadIdx.x >> 6);   // grid covers exactly N_NODES
  int lane = threadIdx.x & 63;

  int s = rowptr[node], epos = rowptr[node + 1];

  float2 acc = *(const float2*)(HS + (size_t)node * DFEAT + lane * 2);
  float a0 = acc.x, a1 = acc.y;

  for (int e = s; e < epos; e += 4) {
    int idx[4];
#pragma unroll
    for (int j = 0; j < 4; j++) idx[j] = (e + j < epos) ? colidx[e + j] : -1;
#pragma unroll
    for (int j = 0; j < 4; j++) {
      if (idx[j] >= 0) {
        float2 v = *(const float2*)(HS + (size_t)idx[j] * DFEAT + lane * 2);
        a0 += v.x;
        a1 += v.y;
      }
    }
  }

  float dv = dinv[node];
  float2 b = *(const float2*)(bias + lane * 2);
  float r0 = a0 * dv + b.x;
  float r1 = a1 * dv + b.y;
  if (do_relu) { r0 = fmaxf(r0, 0.f); r1 = fmaxf(r1, 0.f); }
  float2 o = make_float2(r0, r1);
  *(float2*)(OUT + (size_t)node * DFEAT + lane * 2) = o;
}

// ---------------- pooling: mean over sorted batch ranges ----------------
__device__ __forceinline__ int lower_bound_i(const int* a, int n, int key, int shift) {
  int lo = 0, hi = n;
  while (lo < hi) {
    int mid = (lo + hi) >> 1;
    if (a[mid << shift] < key) lo = mid + 1; else hi = mid;
  }
  return lo;
}

__global__ __launch_bounds__(256) void pool_k(const float* __restrict__ H,
                                              const int* __restrict__ batch,
                                              const int* __restrict__ flag,
                                              float* __restrict__ OUT) {
  int g = blockIdx.x;
  int m = *flag;   // 1 if int64 batch
  int lo = lower_bound_i(batch, N_NODES, g, m);
  int hi = lower_bound_i(batch, N_NODES, g + 1, m);
  int cnt = hi - lo;
  int d = threadIdx.x & 127;
  int half = threadIdx.x >> 7;
  float acc = 0.f;
  for (int row = lo + half; row < hi; row += 2)
    acc += H[(size_t)row * DFEAT + d];
  __shared__ float red[256];
  red[threadIdx.x] = acc;
  __syncthreads();
  if (threadIdx.x < 128) {
    float v = red[threadIdx.x] + red[threadIdx.x + 128];
    v /= fmaxf((float)cnt, 1.0f);
    OUT[g * DFEAT + threadIdx.x] = v;
  }
}

// ---------------- orchestration ----------------

extern "C" void kernel_launch(void* const* d_in, const int* in_sizes, int n_in,
                              void* d_out, int out_size, void* d_ws, size_t ws_size,
                              hipStream_t stream) {
  const float* x   = (const float*)d_in[0];
  const int* ei    = (const int*)d_in[1];   // [2, E] flat (int32 or int64 -> detected)
  const int* batch = (const int*)d_in[2];
  const float* W1  = (const float*)d_in[3];
  const float* b1  = (const float*)d_in[4];
  const float* W2  = (const float*)d_in[5];
  const float* b2  = (const float*)d_in[6];
  const float* W3  = (const float*)d_in[7];
  const float* b3  = (const float*)d_in[8];
  float* out = (float*)d_out;

  // workspace carve-up (256B aligned)
  char* p = (char*)d_ws;
  size_t off = 0;
  auto carve = [&](size_t bytes) -> void* {
    void* q = p + off;
    off = (off + bytes + 255) & ~(size_t)255;
    return q;
  };
  int*   deg    = (int*)carve(N_NODES * 4);
  int*   rowptr = (int*)carve((N_NODES + 1) * 4);
  int*   cursor = (int*)carve(N_NODES * 4);
  int*   blksum = (int*)carve(512 * 4);
  int*   flag   = (int*)carve(256);
  float* dinv   = (float*)carve(N_NODES * 4);
  int*   colarr = (int*)carve((size_t)N_EDGES * 4);
  float* bufA   = (float*)carve((size_t)N_NODES * DFEAT * 4);
  float* bufB   = (float*)carve((size_t)N_NODES * DFEAT * 4);
  (void)ws_size;

  // graph structure (recomputed every call; same inputs -> same result)
  detect_k<<<1, 64, 0, stream>>>(ei, flag);
  init_deg_k<<<NB_N, 256, 0, stream>>>(deg);
  count_k<<<NB_E, 256, 0, stream>>>(ei, flag, deg);
  scan1_k<<<NB_N, 256, 0, stream>>>(deg, rowptr, blksum);
  scan2_k<<<1, 512, 0, stream>>>(blksum);
  scan3_k<<<NB_N, 256, 0, stream>>>(deg, rowptr, cursor, dinv, blksum);
  fill_k<<<NB_E, 256, 0, stream>>>(ei, flag, cursor, colarr);

  const int GB = (N_NODES + 63) / 64;   // 1563
  const int AB = N_NODES / 4;           // 25000

  // layer 1
  gemm_scale_k<<<GB, 256, 0, stream>>>(x, W1, dinv, bufA, N_NODES);
  agg_k<<<AB, 256, 0, stream>>>(bufA, dinv, rowptr, colarr, b1, bufB, 1);
  // layer 2
  gemm_scale_k<<<GB, 256, 0, stream>>>(bufB, W2, dinv, bufA, N_NODES);
  agg_k<<<AB, 256, 0, stream>>>(bufA, dinv, rowptr, colarr, b2, bufB, 1);
  // layer 3 (no relu)
  gemm_scale_k<<<GB, 256, 0, stream>>>(bufB, W3, dinv, bufA, N_NODES);
  agg_k<<<AB, 256, 0, stream>>>(bufA, dinv, rowptr, colarr, b3, bufB, 0);
  // pooling
  pool_k<<<N_GRAPHS, 256, 0, stream>>>(bufB, batch, flag, out);
}